// Round 10
// baseline (379.778 us; speedup 1.0000x reference)
//
#include <hip/hip_runtime.h>

#define AW 264   // fp16 elems per activation LDS row (256 + 8 pad)
#define YW 136   // f32 elems per Ys row (128 + 8 pad)

typedef _Float16 f16x8 __attribute__((ext_vector_type(8)));
typedef _Float16 f16x4 __attribute__((ext_vector_type(4)));
typedef __attribute__((ext_vector_type(4))) float f32x4;

// 5-op tanh: 1 - 2/(e^{2x}+1). Safe at +/-inf. |err| ~1e-7.
__device__ __forceinline__ float fast_tanh(float x) {
    float e = __expf(2.0f * x);
    return 1.0f - 2.0f / (e + 1.0f);
}
// Workgroup barrier ordering LDS only — does NOT drain vmcnt.
__device__ __forceinline__ void bar_lds() {
    asm volatile("s_waitcnt lgkmcnt(0)\n\ts_barrier" ::: "memory");
}

// MFMA with A-operand pinned in AGPRs ("a" class) — weights stay resident,
// zero per-eval global traffic for W1/W2.
#define MFMA_AG(FRAG, B, ACC) \
    asm volatile("v_mfma_f32_16x16x32_f16 %0, %1, %2, %0" \
                 : "+v"(ACC) : "a"(FRAG), "v"(B))
// MFMA with both operands in VGPRs (streamed A_r).
#define MFMA_VV(A, B, ACC) \
    asm volatile("v_mfma_f32_16x16x32_f16 %0, %1, %2, %0" \
                 : "+v"(ACC) : "v"(A), "v"(B))
// Hazard fences around asm MFMAs (VALU->MFMA SrcC and MFMA->VALU RAW).
#define FENCE6(A,B,C,D,E,F) \
    asm volatile("s_nop 7\n\ts_nop 7" : "+v"(A),"+v"(B),"+v"(C),"+v"(D),"+v"(E),"+v"(F))
#define FENCE3(A,B,C) \
    asm volatile("s_nop 7\n\ts_nop 7" : "+v"(A),"+v"(B),"+v"(C))

// one kc-step of stage1/2: 2 n-tiles x 3 chains, weight frags from AGPR
#define S12_KC(AH0,AL0,AH1,AL1, YH, YL) \
    MFMA_AG(AH0, YH, aA0); MFMA_AG(AL0, YH, aB0); MFMA_AG(AH0, YL, aC0); \
    MFMA_AG(AH1, YH, aA1); MFMA_AG(AL1, YH, aB1); MFMA_AG(AH1, YL, aC1)

// ---------------- fused precompute (round-8 version): hi/lo fp16 fragments ----
__global__ __launch_bounds__(256) void pk_all(
    const float* __restrict__ Wvf1, const float* __restrict__ Wvf2,
    const float* __restrict__ Wm,   const float* __restrict__ bm,
    const float* __restrict__ logsig,
    _Float16* __restrict__ W1F, _Float16* __restrict__ W2F,
    _Float16* __restrict__ A3F, float* __restrict__ c_all)
{
    __shared__ float ls[32][62];
    const int b = blockIdx.x, t = threadIdx.x;
    if (b < 128) {                      // W1: N=256 x K=128 (16 nt, 4 kc)
        int u = b * 256 + t;
        int j = u & 7, l = (u >> 3) & 63;
        int kc = (u >> 9) & 3, nt = (u >> 9) >> 2;
        int n = nt * 16 + (l & 15), k = kc * 32 + (l >> 4) * 8 + j;
        float w = Wvf1[n * 128 + k];
        _Float16 hi = (_Float16)w;
        W1F[u] = hi;
        W1F[32768 + u] = (_Float16)(w - (float)hi);
    } else if (b < 384) {               // W2: 256x256 (16 nt, 8 kc)
        int u = (b - 128) * 256 + t;
        int j = u & 7, l = (u >> 3) & 63;
        int kc = (u >> 9) & 7, nt = (u >> 9) >> 3;
        int n = nt * 16 + (l & 15), k = kc * 32 + (l >> 4) * 8 + j;
        float w = Wvf2[n * 256 + k];
        _Float16 hi = (_Float16)w;
        W2F[u] = hi;
        W2F[65536 + u] = (_Float16)(w - (float)hi);
    } else if (b < 896) {               // A_r, r-chunks of 8 (4 chunks x 128 blocks)
        for (int e2 = t; e2 < 32 * 62; e2 += 256)
            ls[e2 / 62][e2 % 62] = logsig[(e2 / 62) * 63 + 1 + (e2 % 62)];
        __syncthreads();
        int idx = b - 384;
        int chunk = idx >> 7;
        int u = (idx & 127) * 256 + t;
        int j = u & 7, l = (u >> 3) & 63, kc = (u >> 9) & 7, nt = (u >> 12) & 7;
        int h = nt * 16 + (l & 15);
        int v = kc * 32 + (l >> 4) * 8 + j;
        int r0 = chunk * 8;
        float acc[8];
#pragma unroll
        for (int r = 0; r < 8; r++) acc[r] = 0.f;
        for (int ll = 0; ll < 62; ll++) {
            float wv2 = Wm[(h * 62 + ll) * 256 + v];
#pragma unroll
            for (int r = 0; r < 8; r++) acc[r] += wv2 * ls[r0 + r][ll];
        }
        for (int r = 0; r < 8; r++) {
            _Float16 hi = (_Float16)acc[r];
            A3F[(r0 + r) * 65536 + u] = hi;
            A3F[(r0 + r) * 65536 + 32768 + u] = (_Float16)(acc[r] - (float)hi);
        }
    } else {                            // c_r[h] = bm[h,:] . seg_r
        int u = (b - 896) * 256 + t;
        int r = u >> 7, h = u & 127;
        float acc = 0.f;
        for (int ll = 0; ll < 62; ll++) acc += bm[h * 62 + ll] * logsig[r * 63 + 1 + ll];
        c_all[u] = acc;
    }
}

// ---------------- main fused kernel: 32 blocks x 16 rows, 8 waves, 20-step Heun ---
// W1+W2 hi/lo fragments RESIDENT IN AGPRS (48 frags = 192 AGPRs/wave, "a"-class
// inline-asm MFMA operands) -> per-eval global traffic drops 640KB -> 128KB (A_r
// windows only). Transposed MFMA form, fp16 hi/lo 3-chain numerics (absmax 0.0039).
__global__ __launch_bounds__(512, 2) void rde_main(
    const float* __restrict__ ts, const float* __restrict__ x0,
    const float* __restrict__ intervals,
    const float* __restrict__ b1g, const float* __restrict__ b2g,
    const float* __restrict__ Win, const float* __restrict__ bin,
    const float* __restrict__ Wout, const float* __restrict__ bout,
    const _Float16* __restrict__ W1F, const _Float16* __restrict__ W2F,
    const _Float16* __restrict__ A3F, const float* __restrict__ c_all,
    float* __restrict__ out)
{
    __shared__ __align__(16) _Float16 P0h[16 * AW], P0l[16 * AW];
    __shared__ __align__(16) _Float16 P1h[16 * AW], P1l[16 * AW];
    __shared__ float Ys[16 * YW];
    __shared__ float ivl[33];
    __shared__ int   r_arr[40];
    __shared__ float s_arr[40];
    __shared__ float lg[16][12];

    const int t    = threadIdx.x;
    const int lane = t & 63;
    const int wv   = t >> 6;        // wave 0..7
    const int m16  = lane & 15;     // batch row within tile
    const int q    = lane >> 4;
    const int row0 = blockIdx.x * 16;

    if (t < 33) ivl[t] = intervals[t];
    __syncthreads();

    const float ts0 = ts[0];
    const float dt  = __fdiv_rn(ts[32] - ts0, 20.0f);   // bit-exact vs reference

    if (t < 40) {   // searchsorted idx + 1/delta for all 40 VF evals
        int i = t >> 1;
        float tv = ts0 + (float)i * dt;
        if (t & 1) tv += dt;
        int p = 0;
        for (int j2 = 0; j2 < 32; j2++) p += (ivl[1 + j2] < tv) ? 1 : 0;
        int idx = p + 1;
        idx = idx < 1 ? 1 : idx;
        idx = idx > 32 ? 32 : idx;
        r_arr[t] = idx - 1;
        s_arr[t] = __fdiv_rn(1.0f, ivl[idx] - ivl[idx - 1]);
    }

    // biases along D rows (q*4+r) for this wave's stage1/2 n-tiles wv*2, wv*2+1
    f32x4 b1f[2], b2f[2];
#pragma unroll
    for (int tt = 0; tt < 2; tt++) {
        b1f[tt] = *(const f32x4*)(b1g + (wv * 2 + tt) * 16 + q * 4);
        b2f[tt] = *(const f32x4*)(b2g + (wv * 2 + tt) * 16 + q * 4);
    }

    // ---- load persistent weight fragments (AGPR residents: 48 frags) ----
    f16x8 w1h[2][4], w1l[2][4];         // 16 frags = 64 AGPRs
#pragma unroll
    for (int tt = 0; tt < 2; tt++)
#pragma unroll
        for (int kc = 0; kc < 4; kc++) {
            const _Float16* bp = W1F + (((wv * 2 + tt) * 4 + kc) * 64 + lane) * 8;
            w1h[tt][kc] = *(const f16x8*)bp;
            w1l[tt][kc] = *(const f16x8*)(bp + 32768);
        }
    f16x8 w2h[2][8], w2l[2][8];         // 32 frags = 128 AGPRs
#pragma unroll
    for (int tt = 0; tt < 2; tt++)
#pragma unroll
        for (int kc = 0; kc < 8; kc++) {
            const _Float16* bp = W2F + (((wv * 2 + tt) * 8 + kc) * 64 + lane) * 8;
            w2h[tt][kc] = *(const f16x8*)bp;
            w2l[tt][kc] = *(const f16x8*)(bp + 65536);
        }

    // y0 = x0 @ Win.T + bin -> Y regs (stage3 D layout: rows q*4+r, col wv*16+m16)
    float Y[4], K1[4];
    {
        const float* xr = x0 + (row0 + m16) * 5;
        float xv[5];
#pragma unroll
        for (int d = 0; d < 5; d++) xv[d] = xr[d];
        int h0 = wv * 16 + q * 4;
        f16x4 hv, lv;
#pragma unroll
        for (int r = 0; r < 4; r++) {
            float acc = bin[h0 + r];
#pragma unroll
            for (int d = 0; d < 5; d++) acc += xv[d] * Win[(h0 + r) * 5 + d];
            Y[r] = acc;
            K1[r] = 0.f;
            _Float16 hi = (_Float16)acc;
            hv[r] = hi;
            lv[r] = (_Float16)(acc - (float)hi);
        }
        *(f16x4*)(P0h + m16 * AW + h0) = hv;
        *(f16x4*)(P0l + m16 * AW + h0) = lv;
    }
    __syncthreads();

    _Float16 *Aih = P0h, *Ail = P0l;    // in buffers
    _Float16 *Aoh = P1h, *Aol = P1l;    // out buffers

#pragma unroll 1
    for (int e = 0; e < 40; e++) {
        const int half = e & 1;
        const int ri   = r_arr[e];
        const float s  = s_arr[e];
        const _Float16* ABase = A3F + ri * 65536;

        // ================ stage1: h1 = relu(W1 . y), K=128 ================
        f32x4 aA0 = b1f[0], aA1 = b1f[1];
        f32x4 aB0 = (f32x4){0.f,0.f,0.f,0.f}, aB1 = aB0, aC0 = aB0, aC1 = aB0;
        FENCE6(aA0, aB0, aC0, aA1, aB1, aC1);   // VALU->MFMA SrcC hazard
        f16x8 yh[4], yl[4];
#pragma unroll
        for (int kc = 0; kc < 4; kc++) {
            int ao = m16 * AW + kc * 32 + q * 8;
            yh[kc] = *(const f16x8*)(Aih + ao);
            yl[kc] = *(const f16x8*)(Ail + ao);
        }
        S12_KC(w1h[0][0], w1l[0][0], w1h[1][0], w1l[1][0], yh[0], yl[0]);
        S12_KC(w1h[0][1], w1l[0][1], w1h[1][1], w1l[1][1], yh[1], yl[1]);
        S12_KC(w1h[0][2], w1l[0][2], w1h[1][2], w1l[1][2], yh[2], yl[2]);
        S12_KC(w1h[0][3], w1l[0][3], w1h[1][3], w1l[1][3], yh[3], yl[3]);
        FENCE6(aA0, aB0, aC0, aA1, aB1, aC1);   // MFMA->VALU hazard
        {
            f16x4 hv, lv;
            int n0 = (wv * 2 + 0) * 16 + q * 4;
#pragma unroll
            for (int r = 0; r < 4; r++) {
                float v = fmaxf(aA0[r] + aB0[r] + aC0[r], 0.f);
                _Float16 hi = (_Float16)v; hv[r] = hi; lv[r] = (_Float16)(v - (float)hi);
            }
            *(f16x4*)(Aoh + m16 * AW + n0) = hv;
            *(f16x4*)(Aol + m16 * AW + n0) = lv;
            int n1 = (wv * 2 + 1) * 16 + q * 4;
#pragma unroll
            for (int r = 0; r < 4; r++) {
                float v = fmaxf(aA1[r] + aB1[r] + aC1[r], 0.f);
                _Float16 hi = (_Float16)v; hv[r] = hi; lv[r] = (_Float16)(v - (float)hi);
            }
            *(f16x4*)(Aoh + m16 * AW + n1) = hv;
            *(f16x4*)(Aol + m16 * AW + n1) = lv;
        }
        bar_lds();

        // ================ stage2: h2 = tanh(W2 . h1), K=256 ================
        aA0 = b2f[0]; aA1 = b2f[1];
        aB0 = (f32x4){0.f,0.f,0.f,0.f}; aB1 = aB0; aC0 = aB0; aC1 = aB0;
        FENCE6(aA0, aB0, aC0, aA1, aB1, aC1);
        f16x8 hh[8], hl[8];
#pragma unroll
        for (int kc = 0; kc < 8; kc++) {
            int ao = m16 * AW + kc * 32 + q * 8;
            hh[kc] = *(const f16x8*)(Aoh + ao);
            hl[kc] = *(const f16x8*)(Aol + ao);
        }
        S12_KC(w2h[0][0], w2l[0][0], w2h[1][0], w2l[1][0], hh[0], hl[0]);
        S12_KC(w2h[0][1], w2l[0][1], w2h[1][1], w2l[1][1], hh[1], hl[1]);
        S12_KC(w2h[0][2], w2l[0][2], w2h[1][2], w2l[1][2], hh[2], hl[2]);
        S12_KC(w2h[0][3], w2l[0][3], w2h[1][3], w2l[1][3], hh[3], hl[3]);
        S12_KC(w2h[0][4], w2l[0][4], w2h[1][4], w2l[1][4], hh[4], hl[4]);
        S12_KC(w2h[0][5], w2l[0][5], w2h[1][5], w2l[1][5], hh[5], hl[5]);
        S12_KC(w2h[0][6], w2l[0][6], w2h[1][6], w2l[1][6], hh[6], hl[6]);
        S12_KC(w2h[0][7], w2l[0][7], w2h[1][7], w2l[1][7], hh[7], hl[7]);
        // issue A_r window A (kc 0..3; stage3 n-tile = wv) + c vector (in flight
        // across the barrier — bar_lds doesn't drain vmcnt)
        f16x8 a3a[4][2];
#pragma unroll
        for (int kc = 0; kc < 4; kc++) {
            const _Float16* bp = ABase + ((wv * 8 + kc) * 64 + lane) * 8;
            a3a[kc][0] = *(const f16x8*)bp;
            a3a[kc][1] = *(const f16x8*)(bp + 32768);
        }
        f32x4 cf = *(const f32x4*)(c_all + ri * 128 + wv * 16 + q * 4);
        FENCE6(aA0, aB0, aC0, aA1, aB1, aC1);
        {
            f16x4 hv, lv;
            int n0 = (wv * 2 + 0) * 16 + q * 4;
#pragma unroll
            for (int r = 0; r < 4; r++) {
                float v = fast_tanh(aA0[r] + aB0[r] + aC0[r]);
                _Float16 hi = (_Float16)v; hv[r] = hi; lv[r] = (_Float16)(v - (float)hi);
            }
            *(f16x4*)(Aih + m16 * AW + n0) = hv;
            *(f16x4*)(Ail + m16 * AW + n0) = lv;
            int n1 = (wv * 2 + 1) * 16 + q * 4;
#pragma unroll
            for (int r = 0; r < 4; r++) {
                float v = fast_tanh(aA1[r] + aB1[r] + aC1[r]);
                _Float16 hi = (_Float16)v; hv[r] = hi; lv[r] = (_Float16)(v - (float)hi);
            }
            *(f16x4*)(Aih + m16 * AW + n1) = hv;
            *(f16x4*)(Ail + m16 * AW + n1) = lv;
        }
        bar_lds();

        // ================ stage3: k = (A_r . h2 + c) * s ================
        f16x8 a3b[4][2];                        // window B (kc 4..7)
#pragma unroll
        for (int kc = 0; kc < 4; kc++) {
            const _Float16* bp = ABase + ((wv * 8 + 4 + kc) * 64 + lane) * 8;
            a3b[kc][0] = *(const f16x8*)bp;
            a3b[kc][1] = *(const f16x8*)(bp + 32768);
        }
        f32x4 kA = cf;
        f32x4 kB = (f32x4){0.f,0.f,0.f,0.f}, kC = kB;
        FENCE3(kA, kB, kC);
#pragma unroll
        for (int kc = 0; kc < 4; kc++) {        // kc 0..3 with a3a
            int ao = m16 * AW + kc * 32 + q * 8;
            f16x8 ah = *(const f16x8*)(Aih + ao);
            f16x8 al = *(const f16x8*)(Ail + ao);
            MFMA_VV(a3a[kc][0], ah, kA);
            MFMA_VV(a3a[kc][1], ah, kB);
            MFMA_VV(a3a[kc][0], al, kC);
        }
#pragma unroll
        for (int kc = 0; kc < 4; kc++) {        // kc 4..7 with a3b
            int ao = m16 * AW + (4 + kc) * 32 + q * 8;
            f16x8 ah = *(const f16x8*)(Aih + ao);
            f16x8 al = *(const f16x8*)(Ail + ao);
            MFMA_VV(a3b[kc][0], ah, kA);
            MFMA_VV(a3b[kc][1], ah, kB);
            MFMA_VV(a3b[kc][0], al, kC);
        }
        FENCE3(kA, kB, kC);
        {                                       // Heun commit + y -> out, packed b64
            int h0 = wv * 16 + q * 4;
            f16x4 hv, lv;
#pragma unroll
            for (int r = 0; r < 4; r++) {
                float kv = (kA[r] + kB[r] + kC[r]) * s;
                float yn;
                if (half == 0) {                 // k1: stash, form y+dt*k1
                    K1[r] = kv;
                    yn = Y[r] + dt * kv;
                } else {                         // k2: y += 0.5*dt*(k1+k2)
                    yn = Y[r] + 0.5f * dt * (K1[r] + kv);
                    Y[r] = yn;
                }
                _Float16 hi = (_Float16)yn;
                hv[r] = hi;
                lv[r] = (_Float16)(yn - (float)hi);
            }
            *(f16x4*)(Aoh + m16 * AW + h0) = hv;
            *(f16x4*)(Aol + m16 * AW + h0) = lv;
        }
        bar_lds();
        _Float16* tp;
        tp = Aih; Aih = Aoh; Aoh = tp;
        tp = Ail; Ail = Aol; Aol = tp;
    }

    // epilogue: Y regs -> Ys f32 [m][h]
#pragma unroll
    for (int r = 0; r < 4; r++)
        Ys[m16 * YW + wv * 16 + q * 4 + r] = Y[r];
    __syncthreads();
    if (t < 160) {                  // logits
        int m = t / 10, c = t % 10;
        float acc = bout[c];
        for (int k = 0; k < 128; k++) acc += Ys[m * YW + k] * Wout[c * 128 + k];
        lg[m][c] = acc;
    }
    __syncthreads();
    if (t < 16) {                   // softmax
        float mx = -1e30f;
#pragma unroll
        for (int c = 0; c < 10; c++) mx = fmaxf(mx, lg[t][c]);
        float ex[10], sum = 0.f;
#pragma unroll
        for (int c = 0; c < 10; c++) { ex[c] = expf(lg[t][c] - mx); sum += ex[c]; }
        float inv = __fdiv_rn(1.0f, sum);
#pragma unroll
        for (int c = 0; c < 10; c++) out[(row0 + t) * 10 + c] = ex[c] * inv;
    }
}

extern "C" void kernel_launch(void* const* d_in, const int* in_sizes, int n_in,
                              void* d_out, int out_size, void* d_ws, size_t ws_size,
                              hipStream_t stream) {
    const float* ts     = (const float*)d_in[0];
    const float* logsig = (const float*)d_in[1];
    const float* x0     = (const float*)d_in[2];
    const float* ivls   = (const float*)d_in[3];
    const float* Wvf1   = (const float*)d_in[4];
    const float* bvf1   = (const float*)d_in[5];
    const float* Wvf2   = (const float*)d_in[6];
    const float* bvf2   = (const float*)d_in[7];
    const float* Wm     = (const float*)d_in[8];
    const float* bm     = (const float*)d_in[9];
    const float* Win    = (const float*)d_in[10];
    const float* bin    = (const float*)d_in[11];
    const float* Wout   = (const float*)d_in[12];
    const float* bout   = (const float*)d_in[13];

    _Float16* W1F = (_Float16*)d_ws;            // 65536 halfs (128KB, hi+lo)
    _Float16* W2F = W1F + 65536;                // 131072 halfs (256KB, hi+lo)
    _Float16* A3F = W2F + 131072;               // 32*65536 halfs (4MB, hi+lo per r)
    float* c_all = (float*)(A3F + 32 * 65536);  // 4096 f32 (16KB)
    float* out = (float*)d_out;

    pk_all<<<dim3(912), dim3(256), 0, stream>>>(Wvf1, Wvf2, Wm, bm, logsig,
                                                W1F, W2F, A3F, c_all);
    rde_main<<<dim3(32), dim3(512), 0, stream>>>(
        ts, x0, ivls, bvf1, bvf2, Win, bin, Wout, bout,
        W1F, W2F, A3F, c_all, out);
}

// Round 11
// 346.358 us; speedup vs baseline: 1.0965x; 1.0965x over previous
//
#include <hip/hip_runtime.h>

#define AW 264   // fp16 elems per activation LDS row (256 + 8 pad)
#define YW 136   // f32 elems per Ys row (128 + 8 pad)

typedef _Float16 f16x8 __attribute__((ext_vector_type(8)));
typedef _Float16 f16x4 __attribute__((ext_vector_type(4)));
typedef __attribute__((ext_vector_type(4))) float f32x4;

// 5-op tanh: 1 - 2/(e^{2x}+1). Safe at +/-inf. |err| ~1e-7.
__device__ __forceinline__ float fast_tanh(float x) {
    float e = __expf(2.0f * x);
    return 1.0f - 2.0f / (e + 1.0f);
}
// Workgroup barrier ordering LDS only — does NOT drain vmcnt, so global
// loads issued before it stay in flight across it.
__device__ __forceinline__ void bar_lds() {
    asm volatile("s_waitcnt lgkmcnt(0)\n\ts_barrier" ::: "memory");
}

// ---------------- fused precompute: weights -> MFMA fragment layout, hi/lo fp16 ----
// F layout: [plane][nt][kc][lane(64)][j(8)]; value = W[n*K+k], n=nt*16+(l&15),
// k=kc*32+(l>>4)*8+j. Same lane formula serves as A- or B-operand fragment.
__global__ __launch_bounds__(256) void pk_all(
    const float* __restrict__ Wvf1, const float* __restrict__ Wvf2,
    const float* __restrict__ Wm,   const float* __restrict__ bm,
    const float* __restrict__ logsig,
    _Float16* __restrict__ W1F, _Float16* __restrict__ W2F,
    _Float16* __restrict__ A3F, float* __restrict__ c_all)
{
    __shared__ float ls[32][62];
    const int b = blockIdx.x, t = threadIdx.x;
    if (b < 128) {                      // W1: N=256 x K=128 (16 nt, 4 kc)
        int u = b * 256 + t;
        int j = u & 7, l = (u >> 3) & 63;
        int kc = (u >> 9) & 3, nt = (u >> 9) >> 2;
        int n = nt * 16 + (l & 15), k = kc * 32 + (l >> 4) * 8 + j;
        float w = Wvf1[n * 128 + k];
        _Float16 hi = (_Float16)w;
        W1F[u] = hi;
        W1F[32768 + u] = (_Float16)(w - (float)hi);
    } else if (b < 384) {               // W2: 256x256 (16 nt, 8 kc)
        int u = (b - 128) * 256 + t;
        int j = u & 7, l = (u >> 3) & 63;
        int kc = (u >> 9) & 7, nt = (u >> 9) >> 3;
        int n = nt * 16 + (l & 15), k = kc * 32 + (l >> 4) * 8 + j;
        float w = Wvf2[n * 256 + k];
        _Float16 hi = (_Float16)w;
        W2F[u] = hi;
        W2F[65536 + u] = (_Float16)(w - (float)hi);
    } else if (b < 896) {               // A_r, r-chunks of 8 (4 chunks x 128 blocks)
        for (int e2 = t; e2 < 32 * 62; e2 += 256)
            ls[e2 / 62][e2 % 62] = logsig[(e2 / 62) * 63 + 1 + (e2 % 62)];
        __syncthreads();
        int idx = b - 384;
        int chunk = idx >> 7;
        int u = (idx & 127) * 256 + t;
        int j = u & 7, l = (u >> 3) & 63, kc = (u >> 9) & 7, nt = (u >> 12) & 7;
        int h = nt * 16 + (l & 15);
        int v = kc * 32 + (l >> 4) * 8 + j;
        int r0 = chunk * 8;
        float acc[8];
#pragma unroll
        for (int r = 0; r < 8; r++) acc[r] = 0.f;
        for (int ll = 0; ll < 62; ll++) {
            float wv2 = Wm[(h * 62 + ll) * 256 + v];
#pragma unroll
            for (int r = 0; r < 8; r++) acc[r] += wv2 * ls[r0 + r][ll];
        }
        for (int r = 0; r < 8; r++) {
            _Float16 hi = (_Float16)acc[r];
            A3F[(r0 + r) * 65536 + u] = hi;
            A3F[(r0 + r) * 65536 + 32768 + u] = (_Float16)(acc[r] - (float)hi);
        }
    } else {                            // c_r[h] = bm[h,:] . seg_r
        int u = (b - 896) * 256 + t;
        int r = u >> 7, h = u & 127;
        float acc = 0.f;
        for (int ll = 0; ll < 62; ll++) acc += bm[h * 62 + ll] * logsig[r * 63 + 1 + ll];
        c_all[u] = acc;
    }
}

// ---------------- main fused kernel: 32 blocks x 16 rows, 8 waves, 20-step Heun ---
// Round-9 structure, but W1 (all) AND W2's first half (kc 0..3) are loop-invariant
// register residents (compiler places long-lived MFMA A-operands in AGPRs).
// Per-eval global streaming drops 512KB -> 256KB (w2b + A_r windows only).
// Transposed MFMA (weights = A-operand), fp16 hi/lo 3-chain (absmax 0.0039).
__global__ __launch_bounds__(512, 2) void rde_main(
    const float* __restrict__ ts, const float* __restrict__ x0,
    const float* __restrict__ intervals,
    const float* __restrict__ b1g, const float* __restrict__ b2g,
    const float* __restrict__ Win, const float* __restrict__ bin,
    const float* __restrict__ Wout, const float* __restrict__ bout,
    const _Float16* __restrict__ W1F, const _Float16* __restrict__ W2F,
    const _Float16* __restrict__ A3F, const float* __restrict__ c_all,
    float* __restrict__ out)
{
    __shared__ __align__(16) _Float16 P0h[16 * AW], P0l[16 * AW];
    __shared__ __align__(16) _Float16 P1h[16 * AW], P1l[16 * AW];
    __shared__ float Ys[16 * YW];
    __shared__ float ivl[33];
    __shared__ int   r_arr[40];
    __shared__ float s_arr[40];
    __shared__ float lg[16][12];

    const int t    = threadIdx.x;
    const int lane = t & 63;
    const int wv   = t >> 6;        // wave 0..7
    const int m16  = lane & 15;     // batch row within tile
    const int q    = lane >> 4;
    const int row0 = blockIdx.x * 16;

    if (t < 33) ivl[t] = intervals[t];
    __syncthreads();

    const float ts0 = ts[0];
    const float dt  = __fdiv_rn(ts[32] - ts0, 20.0f);   // bit-exact vs reference

    if (t < 40) {   // searchsorted idx + 1/delta for all 40 VF evals
        int i = t >> 1;
        float tv = ts0 + (float)i * dt;
        if (t & 1) tv += dt;
        int p = 0;
        for (int j2 = 0; j2 < 32; j2++) p += (ivl[1 + j2] < tv) ? 1 : 0;
        int idx = p + 1;
        idx = idx < 1 ? 1 : idx;
        idx = idx > 32 ? 32 : idx;
        r_arr[t] = idx - 1;
        s_arr[t] = __fdiv_rn(1.0f, ivl[idx] - ivl[idx - 1]);
    }

    // biases along D rows (q*4+r) for this wave's stage1/2 n-tiles wv*2, wv*2+1
    f32x4 b1f[2], b2f[2];
#pragma unroll
    for (int tt = 0; tt < 2; tt++) {
        b1f[tt] = *(const f32x4*)(b1g + (wv * 2 + tt) * 16 + q * 4);
        b2f[tt] = *(const f32x4*)(b2g + (wv * 2 + tt) * 16 + q * 4);
    }

    // ---- loop-invariant register residents ----
    // W1 all kc (16 frags = 64 regs) — loaded ONCE, never re-fetched.
    f16x8 w1f[2][4][2];
#pragma unroll
    for (int tt = 0; tt < 2; tt++)
#pragma unroll
        for (int kc = 0; kc < 4; kc++) {
            const _Float16* bp = W1F + (((wv * 2 + tt) * 4 + kc) * 64 + lane) * 8;
            w1f[tt][kc][0] = *(const f16x8*)bp;
            w1f[tt][kc][1] = *(const f16x8*)(bp + 32768);
        }
    // W2 first half kc 0..3 (16 frags = 64 regs) — loaded ONCE.
    f16x8 w2a[2][4][2];
#pragma unroll
    for (int tt = 0; tt < 2; tt++)
#pragma unroll
        for (int kc = 0; kc < 4; kc++) {
            const _Float16* bp = W2F + (((wv * 2 + tt) * 8 + kc) * 64 + lane) * 8;
            w2a[tt][kc][0] = *(const f16x8*)bp;
            w2a[tt][kc][1] = *(const f16x8*)(bp + 65536);
        }

    // y0 = x0 @ Win.T + bin -> Y regs (stage3 D layout: rows q*4+r, col wv*16+m16)
    float Y[4], K1[4];
    {
        const float* xr = x0 + (row0 + m16) * 5;
        float xv[5];
#pragma unroll
        for (int d = 0; d < 5; d++) xv[d] = xr[d];
        int h0 = wv * 16 + q * 4;
        f16x4 hv, lv;
#pragma unroll
        for (int r = 0; r < 4; r++) {
            float acc = bin[h0 + r];
#pragma unroll
            for (int d = 0; d < 5; d++) acc += xv[d] * Win[(h0 + r) * 5 + d];
            Y[r] = acc;
            K1[r] = 0.f;
            _Float16 hi = (_Float16)acc;
            hv[r] = hi;
            lv[r] = (_Float16)(acc - (float)hi);
        }
        *(f16x4*)(P0h + m16 * AW + h0) = hv;   // 512 thr x 4 = full 16x128 coverage
        *(f16x4*)(P0l + m16 * AW + h0) = lv;
    }
    __syncthreads();

    _Float16 *Aih = P0h, *Ail = P0l;    // in buffers
    _Float16 *Aoh = P1h, *Aol = P1l;    // out buffers

#pragma unroll 1
    for (int e = 0; e < 40; e++) {
        const int half = e & 1;
        const int ri   = r_arr[e];
        const float s  = s_arr[e];
        const _Float16* ABase = A3F + ri * 65536;

        // ---- stage1: h1 = relu(W1 . y), K=128; W1 resident, no loads ----
        f32x4 aA[2], aB[2], aC[2];
#pragma unroll
        for (int tt = 0; tt < 2; tt++) {
            aA[tt] = b1f[tt];
            aB[tt] = (f32x4){0.f, 0.f, 0.f, 0.f};
            aC[tt] = (f32x4){0.f, 0.f, 0.f, 0.f};
        }
#pragma unroll
        for (int kc = 0; kc < 4; kc++) {
            int ao = m16 * AW + kc * 32 + q * 8;
            f16x8 ah = *(const f16x8*)(Aih + ao);
            f16x8 al = *(const f16x8*)(Ail + ao);
#pragma unroll
            for (int tt = 0; tt < 2; tt++) {
                aA[tt] = __builtin_amdgcn_mfma_f32_16x16x32_f16(w1f[tt][kc][0], ah, aA[tt], 0, 0, 0);
                aB[tt] = __builtin_amdgcn_mfma_f32_16x16x32_f16(w1f[tt][kc][1], ah, aB[tt], 0, 0, 0);
                aC[tt] = __builtin_amdgcn_mfma_f32_16x16x32_f16(w1f[tt][kc][0], al, aC[tt], 0, 0, 0);
            }
        }
        // issue W2 window B (kc 4..7) — in flight across the barrier
        f16x8 w2b[2][4][2];
#pragma unroll
        for (int tt = 0; tt < 2; tt++)
#pragma unroll
            for (int kc = 0; kc < 4; kc++) {
                const _Float16* bp = W2F + (((wv * 2 + tt) * 8 + 4 + kc) * 64 + lane) * 8;
                w2b[tt][kc][0] = *(const f16x8*)bp;
                w2b[tt][kc][1] = *(const f16x8*)(bp + 65536);
            }
#pragma unroll
        for (int tt = 0; tt < 2; tt++) {        // commit h1 -> out, packed b64 hi/lo
            int n0 = (wv * 2 + tt) * 16 + q * 4;
            f16x4 hv, lv;
#pragma unroll
            for (int r = 0; r < 4; r++) {       // D: col=lane&15 (m), row=q*4+r (n)
                float v = fmaxf(aA[tt][r] + aB[tt][r] + aC[tt][r], 0.f);
                _Float16 hi = (_Float16)v;
                hv[r] = hi;
                lv[r] = (_Float16)(v - (float)hi);
            }
            *(f16x4*)(Aoh + m16 * AW + n0) = hv;
            *(f16x4*)(Aol + m16 * AW + n0) = lv;
        }
        bar_lds();

        // ---- stage2: h2 = tanh(W2 . h1), K=256; first half resident (w2a) ----
        // issue A_r window A (kc 0..3; stage3 n-tile = wv) + c vector first
        f16x8 a3a[4][2];
#pragma unroll
        for (int kc = 0; kc < 4; kc++) {
            const _Float16* bp = ABase + ((wv * 8 + kc) * 64 + lane) * 8;
            a3a[kc][0] = *(const f16x8*)bp;
            a3a[kc][1] = *(const f16x8*)(bp + 32768);
        }
        f32x4 cf = *(const f32x4*)(c_all + ri * 128 + wv * 16 + q * 4);
#pragma unroll
        for (int tt = 0; tt < 2; tt++) {
            aA[tt] = b2f[tt];
            aB[tt] = (f32x4){0.f, 0.f, 0.f, 0.f};
            aC[tt] = (f32x4){0.f, 0.f, 0.f, 0.f};
        }
#pragma unroll
        for (int kc = 0; kc < 4; kc++) {        // first half with resident w2a
            int ao = m16 * AW + kc * 32 + q * 8;
            f16x8 ah = *(const f16x8*)(Aoh + ao);
            f16x8 al = *(const f16x8*)(Aol + ao);
#pragma unroll
            for (int tt = 0; tt < 2; tt++) {
                aA[tt] = __builtin_amdgcn_mfma_f32_16x16x32_f16(w2a[tt][kc][0], ah, aA[tt], 0, 0, 0);
                aB[tt] = __builtin_amdgcn_mfma_f32_16x16x32_f16(w2a[tt][kc][1], ah, aB[tt], 0, 0, 0);
                aC[tt] = __builtin_amdgcn_mfma_f32_16x16x32_f16(w2a[tt][kc][0], al, aC[tt], 0, 0, 0);
            }
        }
        // issue A_r window B (kc 4..7)
        f16x8 a3b[4][2];
#pragma unroll
        for (int kc = 0; kc < 4; kc++) {
            const _Float16* bp = ABase + ((wv * 8 + 4 + kc) * 64 + lane) * 8;
            a3b[kc][0] = *(const f16x8*)bp;
            a3b[kc][1] = *(const f16x8*)(bp + 32768);
        }
#pragma unroll
        for (int kc = 0; kc < 4; kc++) {        // second half with streamed w2b
            int ao = m16 * AW + (4 + kc) * 32 + q * 8;
            f16x8 ah = *(const f16x8*)(Aoh + ao);
            f16x8 al = *(const f16x8*)(Aol + ao);
#pragma unroll
            for (int tt = 0; tt < 2; tt++) {
                aA[tt] = __builtin_amdgcn_mfma_f32_16x16x32_f16(w2b[tt][kc][0], ah, aA[tt], 0, 0, 0);
                aB[tt] = __builtin_amdgcn_mfma_f32_16x16x32_f16(w2b[tt][kc][1], ah, aB[tt], 0, 0, 0);
                aC[tt] = __builtin_amdgcn_mfma_f32_16x16x32_f16(w2b[tt][kc][0], al, aC[tt], 0, 0, 0);
            }
        }
#pragma unroll
        for (int tt = 0; tt < 2; tt++) {        // commit h2 (tanh) -> in, packed b64
            int n0 = (wv * 2 + tt) * 16 + q * 4;
            f16x4 hv, lv;
#pragma unroll
            for (int r = 0; r < 4; r++) {
                float v = fast_tanh(aA[tt][r] + aB[tt][r] + aC[tt][r]);
                _Float16 hi = (_Float16)v;
                hv[r] = hi;
                lv[r] = (_Float16)(v - (float)hi);
            }
            *(f16x4*)(Aih + m16 * AW + n0) = hv;
            *(f16x4*)(Ail + m16 * AW + n0) = lv;
        }
        bar_lds();

        // ---- stage3: k = (A_r . h2 + c) * s; no prefetches needed ----
        f32x4 kA = cf;
        f32x4 kB = (f32x4){0.f, 0.f, 0.f, 0.f};
        f32x4 kC = (f32x4){0.f, 0.f, 0.f, 0.f};
#pragma unroll
        for (int kc = 0; kc < 4; kc++) {        // kc 0..3 with a3a
            int ao = m16 * AW + kc * 32 + q * 8;
            f16x8 ah = *(const f16x8*)(Aih + ao);
            f16x8 al = *(const f16x8*)(Ail + ao);
            kA = __builtin_amdgcn_mfma_f32_16x16x32_f16(a3a[kc][0], ah, kA, 0, 0, 0);
            kB = __builtin_amdgcn_mfma_f32_16x16x32_f16(a3a[kc][1], ah, kB, 0, 0, 0);
            kC = __builtin_amdgcn_mfma_f32_16x16x32_f16(a3a[kc][0], al, kC, 0, 0, 0);
        }
#pragma unroll
        for (int kc = 0; kc < 4; kc++) {        // kc 4..7 with a3b
            int ao = m16 * AW + (4 + kc) * 32 + q * 8;
            f16x8 ah = *(const f16x8*)(Aih + ao);
            f16x8 al = *(const f16x8*)(Ail + ao);
            kA = __builtin_amdgcn_mfma_f32_16x16x32_f16(a3b[kc][0], ah, kA, 0, 0, 0);
            kB = __builtin_amdgcn_mfma_f32_16x16x32_f16(a3b[kc][1], ah, kB, 0, 0, 0);
            kC = __builtin_amdgcn_mfma_f32_16x16x32_f16(a3b[kc][0], al, kC, 0, 0, 0);
        }
        {                                       // Heun commit + y -> out, packed b64
            int h0 = wv * 16 + q * 4;
            f16x4 hv, lv;
#pragma unroll
            for (int r = 0; r < 4; r++) {
                float kv = (kA[r] + kB[r] + kC[r]) * s;
                float yn;
                if (half == 0) {                 // k1: stash, form y+dt*k1
                    K1[r] = kv;
                    yn = Y[r] + dt * kv;
                } else {                         // k2: y += 0.5*dt*(k1+k2)
                    yn = Y[r] + 0.5f * dt * (K1[r] + kv);
                    Y[r] = yn;
                }
                _Float16 hi = (_Float16)yn;
                hv[r] = hi;
                lv[r] = (_Float16)(yn - (float)hi);
            }
            *(f16x4*)(Aoh + m16 * AW + h0) = hv;
            *(f16x4*)(Aol + m16 * AW + h0) = lv;
        }
        bar_lds();
        _Float16* tp;
        tp = Aih; Aih = Aoh; Aoh = tp;
        tp = Ail; Ail = Aol; Aol = tp;
    }

    // epilogue: Y regs -> Ys f32 [m][h]
#pragma unroll
    for (int r = 0; r < 4; r++)
        Ys[m16 * YW + wv * 16 + q * 4 + r] = Y[r];
    __syncthreads();
    if (t < 160) {                  // logits
        int m = t / 10, c = t % 10;
        float acc = bout[c];
        for (int k = 0; k < 128; k++) acc += Ys[m * YW + k] * Wout[c * 128 + k];
        lg[m][c] = acc;
    }
    __syncthreads();
    if (t < 16) {                   // softmax
        float mx = -1e30f;
#pragma unroll
        for (int c = 0; c < 10; c++) mx = fmaxf(mx, lg[t][c]);
        float ex[10], sum = 0.f;
#pragma unroll
        for (int c = 0; c < 10; c++) { ex[c] = expf(lg[t][c] - mx); sum += ex[c]; }
        float inv = __fdiv_rn(1.0f, sum);
#pragma unroll
        for (int c = 0; c < 10; c++) out[(row0 + t) * 10 + c] = ex[c] * inv;
    }
}

extern "C" void kernel_launch(void* const* d_in, const int* in_sizes, int n_in,
                              void* d_out, int out_size, void* d_ws, size_t ws_size,
                              hipStream_t stream) {
    const float* ts     = (const float*)d_in[0];
    const float* logsig = (const float*)d_in[1];
    const float* x0     = (const float*)d_in[2];
    const float* ivls   = (const float*)d_in[3];
    const float* Wvf1   = (const float*)d_in[4];
    const float* bvf1   = (const float*)d_in[5];
    const float* Wvf2   = (const float*)d_in[6];
    const float* bvf2   = (const float*)d_in[7];
    const float* Wm     = (const float*)d_in[8];
    const float* bm     = (const float*)d_in[9];
    const float* Win    = (const float*)d_in[10];
    const float* bin    = (const float*)d_in[11];
    const float* Wout   = (const float*)d_in[12];
    const float* bout   = (const float*)d_in[13];

    _Float16* W1F = (_Float16*)d_ws;            // 65536 halfs (128KB, hi+lo)
    _Float16* W2F = W1F + 65536;                // 131072 halfs (256KB, hi+lo)
    _Float16* A3F = W2F + 131072;               // 32*65536 halfs (4MB, hi+lo per r)
    float* c_all = (float*)(A3F + 32 * 65536);  // 4096 f32 (16KB)
    float* out = (float*)d_out;

    pk_all<<<dim3(912), dim3(256), 0, stream>>>(Wvf1, Wvf2, Wm, bm, logsig,
                                                W1F, W2F, A3F, c_all);
    rde_main<<<dim3(32), dim3(512), 0, stream>>>(
        ts, x0, ivls, bvf1, bvf2, Win, bin, Wout, bout,
        W1F, W2F, A3F, c_all, out);
}

// Round 12
// 268.112 us; speedup vs baseline: 1.4165x; 1.2918x over previous
//
#include <hip/hip_runtime.h>

#define AW 264   // fp16 elems per activation LDS row (256 + 8 pad)
#define YW 136   // f32 elems per Ys row (128 + 8 pad)

typedef _Float16 f16x8 __attribute__((ext_vector_type(8)));
typedef _Float16 f16x4 __attribute__((ext_vector_type(4)));
typedef __attribute__((ext_vector_type(4))) float f32x4;

// 5-op tanh: 1 - 2/(e^{2x}+1). Safe at +/-inf. |err| ~1e-7.
__device__ __forceinline__ float fast_tanh(float x) {
    float e = __expf(2.0f * x);
    return 1.0f - 2.0f / (e + 1.0f);
}
// Workgroup barrier ordering LDS only — does NOT drain vmcnt, so global
// loads issued before it stay in flight across it.
__device__ __forceinline__ void bar_lds() {
    asm volatile("s_waitcnt lgkmcnt(0)\n\ts_barrier" ::: "memory");
}

// ---------------- fused precompute: weights -> MFMA fragment layout, hi/lo fp16 ----
// F layout: [plane][nt][kc][lane(64)][j(8)]; value = W[n*K+k], n=nt*16+(l&15),
// k=kc*32+(l>>4)*8+j. Same lane formula serves as A- or B-operand fragment.
__global__ __launch_bounds__(256) void pk_all(
    const float* __restrict__ Wvf1, const float* __restrict__ Wvf2,
    const float* __restrict__ Wm,   const float* __restrict__ bm,
    const float* __restrict__ logsig,
    _Float16* __restrict__ W1F, _Float16* __restrict__ W2F,
    _Float16* __restrict__ A3F, float* __restrict__ c_all)
{
    __shared__ float ls[32][62];
    const int b = blockIdx.x, t = threadIdx.x;
    if (b < 128) {                      // W1: N=256 x K=128 (16 nt, 4 kc)
        int u = b * 256 + t;
        int j = u & 7, l = (u >> 3) & 63;
        int kc = (u >> 9) & 3, nt = (u >> 9) >> 2;
        int n = nt * 16 + (l & 15), k = kc * 32 + (l >> 4) * 8 + j;
        float w = Wvf1[n * 128 + k];
        _Float16 hi = (_Float16)w;
        W1F[u] = hi;
        W1F[32768 + u] = (_Float16)(w - (float)hi);
    } else if (b < 384) {               // W2: 256x256 (16 nt, 8 kc)
        int u = (b - 128) * 256 + t;
        int j = u & 7, l = (u >> 3) & 63;
        int kc = (u >> 9) & 7, nt = (u >> 9) >> 3;
        int n = nt * 16 + (l & 15), k = kc * 32 + (l >> 4) * 8 + j;
        float w = Wvf2[n * 256 + k];
        _Float16 hi = (_Float16)w;
        W2F[u] = hi;
        W2F[65536 + u] = (_Float16)(w - (float)hi);
    } else if (b < 896) {               // A_r, r-chunks of 8 (4 chunks x 128 blocks)
        for (int e2 = t; e2 < 32 * 62; e2 += 256)
            ls[e2 / 62][e2 % 62] = logsig[(e2 / 62) * 63 + 1 + (e2 % 62)];
        __syncthreads();
        int idx = b - 384;
        int chunk = idx >> 7;
        int u = (idx & 127) * 256 + t;
        int j = u & 7, l = (u >> 3) & 63, kc = (u >> 9) & 7, nt = (u >> 12) & 7;
        int h = nt * 16 + (l & 15);
        int v = kc * 32 + (l >> 4) * 8 + j;
        int r0 = chunk * 8;
        float acc[8];
#pragma unroll
        for (int r = 0; r < 8; r++) acc[r] = 0.f;
        for (int ll = 0; ll < 62; ll++) {
            float wv2 = Wm[(h * 62 + ll) * 256 + v];
#pragma unroll
            for (int r = 0; r < 8; r++) acc[r] += wv2 * ls[r0 + r][ll];
        }
        for (int r = 0; r < 8; r++) {
            _Float16 hi = (_Float16)acc[r];
            A3F[(r0 + r) * 65536 + u] = hi;
            A3F[(r0 + r) * 65536 + 32768 + u] = (_Float16)(acc[r] - (float)hi);
        }
    } else {                            // c_r[h] = bm[h,:] . seg_r
        int u = (b - 896) * 256 + t;
        int r = u >> 7, h = u & 127;
        float acc = 0.f;
        for (int ll = 0; ll < 62; ll++) acc += bm[h * 62 + ll] * logsig[r * 63 + 1 + ll];
        c_all[u] = acc;
    }
}

// ---------------- main fused kernel: 32 blocks x 16 rows, 8 waves, 20-step Heun ---
// W1 hi/lo RESIDENT IN LDS (128 KB, loaded once) -> per-eval global streaming
// drops 512KB -> 384KB (W2 + A_r windows only) AND frees 64 registers.
// In-place hi/lo act buffer (read-all / barrier / commit / barrier, 6 bar/eval).
// Transposed MFMA (weights = A-operand), fp16 hi/lo 3-chain (absmax 0.0039).
__global__ __launch_bounds__(512, 2) void rde_main(
    const float* __restrict__ ts, const float* __restrict__ x0,
    const float* __restrict__ intervals,
    const float* __restrict__ b1g, const float* __restrict__ b2g,
    const float* __restrict__ Win, const float* __restrict__ bin,
    const float* __restrict__ Wout, const float* __restrict__ bout,
    const _Float16* __restrict__ W1F, const _Float16* __restrict__ W2F,
    const _Float16* __restrict__ A3F, const float* __restrict__ c_all,
    float* __restrict__ out)
{
    __shared__ __align__(16) _Float16 W1s[65536];                 // 128 KB hi+lo
    __shared__ __align__(16) _Float16 AH[16 * AW], AL[16 * AW];   // in-place acts
    __shared__ float Ys[16 * YW];
    __shared__ float ivl[33];
    __shared__ int   r_arr[40];
    __shared__ float s_arr[40];
    __shared__ float lg[16][12];

    const int t    = threadIdx.x;
    const int lane = t & 63;
    const int wv   = t >> 6;        // wave 0..7
    const int m16  = lane & 15;     // batch row within tile
    const int q    = lane >> 4;
    const int row0 = blockIdx.x * 16;

    if (t < 33) ivl[t] = intervals[t];
    // W1 hi+lo -> LDS once: 65536 halfs = 8192 uint4
    for (int e2 = t; e2 < 8192; e2 += 512)
        ((uint4*)W1s)[e2] = ((const uint4*)W1F)[e2];
    __syncthreads();

    const float ts0 = ts[0];
    const float dt  = __fdiv_rn(ts[32] - ts0, 20.0f);   // bit-exact vs reference

    if (t < 40) {   // searchsorted idx + 1/delta for all 40 VF evals
        int i = t >> 1;
        float tv = ts0 + (float)i * dt;
        if (t & 1) tv += dt;
        int p = 0;
        for (int j2 = 0; j2 < 32; j2++) p += (ivl[1 + j2] < tv) ? 1 : 0;
        int idx = p + 1;
        idx = idx < 1 ? 1 : idx;
        idx = idx > 32 ? 32 : idx;
        r_arr[t] = idx - 1;
        s_arr[t] = __fdiv_rn(1.0f, ivl[idx] - ivl[idx - 1]);
    }

    // biases along D rows (q*4+r) for this wave's stage1/2 n-tiles wv*2, wv*2+1
    f32x4 b1f[2], b2f[2];
#pragma unroll
    for (int tt = 0; tt < 2; tt++) {
        b1f[tt] = *(const f32x4*)(b1g + (wv * 2 + tt) * 16 + q * 4);
        b2f[tt] = *(const f32x4*)(b2g + (wv * 2 + tt) * 16 + q * 4);
    }

    // y0 = x0 @ Win.T + bin -> Y regs (stage3 D layout: rows q*4+r, col wv*16+m16)
    float Y[4], K1[4];
    {
        const float* xr = x0 + (row0 + m16) * 5;
        float xv[5];
#pragma unroll
        for (int d = 0; d < 5; d++) xv[d] = xr[d];
        int h0 = wv * 16 + q * 4;
        f16x4 hv, lv;
#pragma unroll
        for (int r = 0; r < 4; r++) {
            float acc = bin[h0 + r];
#pragma unroll
            for (int d = 0; d < 5; d++) acc += xv[d] * Win[(h0 + r) * 5 + d];
            Y[r] = acc;
            K1[r] = 0.f;
            _Float16 hi = (_Float16)acc;
            hv[r] = hi;
            lv[r] = (_Float16)(acc - (float)hi);
        }
        *(f16x4*)(AH + m16 * AW + h0) = hv;    // 512 thr x 4 = full 16x128 coverage
        *(f16x4*)(AL + m16 * AW + h0) = lv;
    }
    __syncthreads();

#pragma unroll 1
    for (int e = 0; e < 40; e++) {
        const int half = e & 1;
        const int ri   = r_arr[e];
        const float s  = s_arr[e];
        const _Float16* ABase = A3F + ri * 65536;

        // ---- stage1: h1 = relu(W1 . y), K=128; W1 frags from LDS ----
        // issue W2 window A (kc 0..3) first — in flight across all of stage1
        f16x8 w2a[2][4][2];
#pragma unroll
        for (int tt = 0; tt < 2; tt++)
#pragma unroll
            for (int kc = 0; kc < 4; kc++) {
                const _Float16* bp = W2F + (((wv * 2 + tt) * 8 + kc) * 64 + lane) * 8;
                w2a[tt][kc][0] = *(const f16x8*)bp;
                w2a[tt][kc][1] = *(const f16x8*)(bp + 65536);
            }
        f32x4 aA[2], aB[2], aC[2];
#pragma unroll
        for (int tt = 0; tt < 2; tt++) {
            aA[tt] = b1f[tt];
            aB[tt] = (f32x4){0.f, 0.f, 0.f, 0.f};
            aC[tt] = (f32x4){0.f, 0.f, 0.f, 0.f};
        }
#pragma unroll
        for (int kc = 0; kc < 4; kc++) {
            int ao = m16 * AW + kc * 32 + q * 8;
            f16x8 ah = *(const f16x8*)(AH + ao);
            f16x8 al = *(const f16x8*)(AL + ao);
#pragma unroll
            for (int tt = 0; tt < 2; tt++) {
                int wb = (((wv * 2 + tt) * 4 + kc) * 64 + lane) * 8;
                f16x8 bh = *(const f16x8*)(W1s + wb);
                f16x8 bl = *(const f16x8*)(W1s + 32768 + wb);
                aA[tt] = __builtin_amdgcn_mfma_f32_16x16x32_f16(bh, ah, aA[tt], 0, 0, 0);
                aB[tt] = __builtin_amdgcn_mfma_f32_16x16x32_f16(bl, ah, aB[tt], 0, 0, 0);
                aC[tt] = __builtin_amdgcn_mfma_f32_16x16x32_f16(bh, al, aC[tt], 0, 0, 0);
            }
        }
        bar_lds();                              // all reads of y / W1 done
#pragma unroll
        for (int tt = 0; tt < 2; tt++) {        // commit h1 in-place, packed b64
            int n0 = (wv * 2 + tt) * 16 + q * 4;
            f16x4 hv, lv;
#pragma unroll
            for (int r = 0; r < 4; r++) {       // D: col=lane&15 (m), row=q*4+r (n)
                float v = fmaxf(aA[tt][r] + aB[tt][r] + aC[tt][r], 0.f);
                _Float16 hi = (_Float16)v;
                hv[r] = hi;
                lv[r] = (_Float16)(v - (float)hi);
            }
            *(f16x4*)(AH + m16 * AW + n0) = hv;
            *(f16x4*)(AL + m16 * AW + n0) = lv;
        }
        bar_lds();

        // ---- stage2: h2 = tanh(W2 . h1), K=256; w2a preloaded, w2b issued now ----
        f16x8 w2b[2][4][2];
#pragma unroll
        for (int tt = 0; tt < 2; tt++)
#pragma unroll
            for (int kc = 0; kc < 4; kc++) {
                const _Float16* bp = W2F + (((wv * 2 + tt) * 8 + 4 + kc) * 64 + lane) * 8;
                w2b[tt][kc][0] = *(const f16x8*)bp;
                w2b[tt][kc][1] = *(const f16x8*)(bp + 65536);
            }
#pragma unroll
        for (int tt = 0; tt < 2; tt++) {
            aA[tt] = b2f[tt];
            aB[tt] = (f32x4){0.f, 0.f, 0.f, 0.f};
            aC[tt] = (f32x4){0.f, 0.f, 0.f, 0.f};
        }
#pragma unroll
        for (int kc = 0; kc < 4; kc++) {        // first half with w2a
            int ao = m16 * AW + kc * 32 + q * 8;
            f16x8 ah = *(const f16x8*)(AH + ao);
            f16x8 al = *(const f16x8*)(AL + ao);
#pragma unroll
            for (int tt = 0; tt < 2; tt++) {
                aA[tt] = __builtin_amdgcn_mfma_f32_16x16x32_f16(w2a[tt][kc][0], ah, aA[tt], 0, 0, 0);
                aB[tt] = __builtin_amdgcn_mfma_f32_16x16x32_f16(w2a[tt][kc][1], ah, aB[tt], 0, 0, 0);
                aC[tt] = __builtin_amdgcn_mfma_f32_16x16x32_f16(w2a[tt][kc][0], al, aC[tt], 0, 0, 0);
            }
        }
        // issue A_r window A (kc 0..3; stage3 n-tile = wv) + c vector
        f16x8 a3a[4][2];
#pragma unroll
        for (int kc = 0; kc < 4; kc++) {
            const _Float16* bp = ABase + ((wv * 8 + kc) * 64 + lane) * 8;
            a3a[kc][0] = *(const f16x8*)bp;
            a3a[kc][1] = *(const f16x8*)(bp + 32768);
        }
        f32x4 cf = *(const f32x4*)(c_all + ri * 128 + wv * 16 + q * 4);
#pragma unroll
        for (int kc = 0; kc < 4; kc++) {        // second half with w2b
            int ao = m16 * AW + (4 + kc) * 32 + q * 8;
            f16x8 ah = *(const f16x8*)(AH + ao);
            f16x8 al = *(const f16x8*)(AL + ao);
#pragma unroll
            for (int tt = 0; tt < 2; tt++) {
                aA[tt] = __builtin_amdgcn_mfma_f32_16x16x32_f16(w2b[tt][kc][0], ah, aA[tt], 0, 0, 0);
                aB[tt] = __builtin_amdgcn_mfma_f32_16x16x32_f16(w2b[tt][kc][1], ah, aB[tt], 0, 0, 0);
                aC[tt] = __builtin_amdgcn_mfma_f32_16x16x32_f16(w2b[tt][kc][0], al, aC[tt], 0, 0, 0);
            }
        }
        // issue A_r window B (kc 4..7)
        f16x8 a3b[4][2];
#pragma unroll
        for (int kc = 0; kc < 4; kc++) {
            const _Float16* bp = ABase + ((wv * 8 + 4 + kc) * 64 + lane) * 8;
            a3b[kc][0] = *(const f16x8*)bp;
            a3b[kc][1] = *(const f16x8*)(bp + 32768);
        }
        bar_lds();                              // all reads of h1 done
#pragma unroll
        for (int tt = 0; tt < 2; tt++) {        // commit h2 (tanh) in-place
            int n0 = (wv * 2 + tt) * 16 + q * 4;
            f16x4 hv, lv;
#pragma unroll
            for (int r = 0; r < 4; r++) {
                float v = fast_tanh(aA[tt][r] + aB[tt][r] + aC[tt][r]);
                _Float16 hi = (_Float16)v;
                hv[r] = hi;
                lv[r] = (_Float16)(v - (float)hi);
            }
            *(f16x4*)(AH + m16 * AW + n0) = hv;
            *(f16x4*)(AL + m16 * AW + n0) = lv;
        }
        bar_lds();

        // ---- stage3: k = (A_r . h2 + c) * s ----
        f32x4 kA = cf;
        f32x4 kB = (f32x4){0.f, 0.f, 0.f, 0.f};
        f32x4 kC = (f32x4){0.f, 0.f, 0.f, 0.f};
#pragma unroll
        for (int kc = 0; kc < 4; kc++) {        // kc 0..3 with a3a
            int ao = m16 * AW + kc * 32 + q * 8;
            f16x8 ah = *(const f16x8*)(AH + ao);
            f16x8 al = *(const f16x8*)(AL + ao);
            kA = __builtin_amdgcn_mfma_f32_16x16x32_f16(a3a[kc][0], ah, kA, 0, 0, 0);
            kB = __builtin_amdgcn_mfma_f32_16x16x32_f16(a3a[kc][1], ah, kB, 0, 0, 0);
            kC = __builtin_amdgcn_mfma_f32_16x16x32_f16(a3a[kc][0], al, kC, 0, 0, 0);
        }
#pragma unroll
        for (int kc = 0; kc < 4; kc++) {        // kc 4..7 with a3b
            int ao = m16 * AW + (4 + kc) * 32 + q * 8;
            f16x8 ah = *(const f16x8*)(AH + ao);
            f16x8 al = *(const f16x8*)(AL + ao);
            kA = __builtin_amdgcn_mfma_f32_16x16x32_f16(a3b[kc][0], ah, kA, 0, 0, 0);
            kB = __builtin_amdgcn_mfma_f32_16x16x32_f16(a3b[kc][1], ah, kB, 0, 0, 0);
            kC = __builtin_amdgcn_mfma_f32_16x16x32_f16(a3b[kc][0], al, kC, 0, 0, 0);
        }
        bar_lds();                              // all reads of h2 done
        {                                       // Heun commit + y' -> in-place b64
            int h0 = wv * 16 + q * 4;
            f16x4 hv, lv;
#pragma unroll
            for (int r = 0; r < 4; r++) {
                float kv = (kA[r] + kB[r] + kC[r]) * s;
                float yn;
                if (half == 0) {                 // k1: stash, form y+dt*k1
                    K1[r] = kv;
                    yn = Y[r] + dt * kv;
                } else {                         // k2: y += 0.5*dt*(k1+k2)
                    yn = Y[r] + 0.5f * dt * (K1[r] + kv);
                    Y[r] = yn;
                }
                _Float16 hi = (_Float16)yn;
                hv[r] = hi;
                lv[r] = (_Float16)(yn - (float)hi);
            }
            *(f16x4*)(AH + m16 * AW + h0) = hv;
            *(f16x4*)(AL + m16 * AW + h0) = lv;
        }
        bar_lds();
    }

    // epilogue: Y regs -> Ys f32 [m][h]
#pragma unroll
    for (int r = 0; r < 4; r++)
        Ys[m16 * YW + wv * 16 + q * 4 + r] = Y[r];
    __syncthreads();
    if (t < 160) {                  // logits
        int m = t / 10, c = t % 10;
        float acc = bout[c];
        for (int k = 0; k < 128; k++) acc += Ys[m * YW + k] * Wout[c * 128 + k];
        lg[m][c] = acc;
    }
    __syncthreads();
    if (t < 16) {                   // softmax
        float mx = -1e30f;
#pragma unroll
        for (int c = 0; c < 10; c++) mx = fmaxf(mx, lg[t][c]);
        float ex[10], sum = 0.f;
#pragma unroll
        for (int c = 0; c < 10; c++) { ex[c] = expf(lg[t][c] - mx); sum += ex[c]; }
        float inv = __fdiv_rn(1.0f, sum);
#pragma unroll
        for (int c = 0; c < 10; c++) out[(row0 + t) * 10 + c] = ex[c] * inv;
    }
}

extern "C" void kernel_launch(void* const* d_in, const int* in_sizes, int n_in,
                              void* d_out, int out_size, void* d_ws, size_t ws_size,
                              hipStream_t stream) {
    const float* ts     = (const float*)d_in[0];
    const float* logsig = (const float*)d_in[1];
    const float* x0     = (const float*)d_in[2];
    const float* ivls   = (const float*)d_in[3];
    const float* Wvf1   = (const float*)d_in[4];
    const float* bvf1   = (const float*)d_in[5];
    const float* Wvf2   = (const float*)d_in[6];
    const float* bvf2   = (const float*)d_in[7];
    const float* Wm     = (const float*)d_in[8];
    const float* bm     = (const float*)d_in[9];
    const float* Win    = (const float*)d_in[10];
    const float* bin    = (const float*)d_in[11];
    const float* Wout   = (const float*)d_in[12];
    const float* bout   = (const float*)d_in[13];

    _Float16* W1F = (_Float16*)d_ws;            // 65536 halfs (128KB, hi+lo)
    _Float16* W2F = W1F + 65536;                // 131072 halfs (256KB, hi+lo)
    _Float16* A3F = W2F + 131072;               // 32*65536 halfs (4MB, hi+lo per r)
    float* c_all = (float*)(A3F + 32 * 65536);  // 4096 f32 (16KB)
    float* out = (float*)d_out;

    pk_all<<<dim3(912), dim3(256), 0, stream>>>(Wvf1, Wvf2, Wm, bm, logsig,
                                                W1F, W2F, A3F, c_all);
    rde_main<<<dim3(32), dim3(512), 0, stream>>>(
        ts, x0, ivls, bvf1, bvf2, Win, bin, Wout, bout,
        W1F, W2F, A3F, c_all, out);
}